// Round 13
// baseline (210.797 us; speedup 1.0000x reference)
//
#include <hip/hip_runtime.h>

// SAR quantizer: q, Q, Wn outputs.
// L=524288 rows, A=24 ADCs, B=8 bits, M=36 coefficient rows.
// VR = VREF = 1.8 / 2^3 = 0.225, noise scale = 0.01**0.5 = 0.1.
//
// R13 = R12 minus the LDS staging (single change): Q stored DIRECTLY per
// lane as two nt f32x4 (32B at elem*32). The two instructions cover
// complementary halves of the same 64B lines back-to-back, so the
// write-combine queue should merge them into full lines. The LDS staging
// was justified on the CACHED path (R1: 150->132us); on the nt path it
// may be pure overhead (8 DS instr + lgkmcnt in every iteration's store
// dependency chain).
//   combining works -> ~88-93us (keep, simpler kernel)
//   combining fails -> ~140-190us (revert, mechanism pinned)

#define L_TOT   524288
#define A_ADC   24
#define M_ROWS  36
#define B_BITS  8
#define BLK     256
#define NBLK    3072
#define NXCD    8
#define N_TOT   (L_TOT * A_ADC)          // 12,582,912
#define T_STR   (NBLK * BLK)             // 786,432 (multiple of 24); N = 16*T

typedef float f32x4 __attribute__((ext_vector_type(4)));

__global__ __launch_bounds__(BLK) void sar_kernel(
    const float* __restrict__ x,
    const float* __restrict__ W,
    const float* __restrict__ nz,
    float* __restrict__ out_q,
    float* __restrict__ out_Q,
    float* __restrict__ out_Wn)
{
    // Bijective XCD swizzle (NBLK % 8 == 0).
    const int bid = blockIdx.x;
    const int sb  = (bid & (NXCD - 1)) * (NBLK / NXCD) + (bid >> 3);

    const int gid = sb * BLK + threadIdx.x;   // < T_STR; 32-bit safe
    const int a = gid % 24;          // ADC column of element gid (+ m*T_STR)

    // Per-a coefficients: c[r] = (W[r][a] + noise[r][a]*0.1f) * 0.225f
    float c[M_ROWS];
#pragma unroll
    for (int r = 0; r < M_ROWS; ++r) {
        float wn = W[r * A_ADC + a] + nz[r * A_ADC + a] * 0.1f;
        c[r] = wn * 0.225f;
    }

    // Wn tail output (864 floats), once (gid is a bijection of thread id).
    if (gid < M_ROWS * A_ADC) {
        __builtin_nontemporal_store(W[gid] + nz[gid] * 0.1f, &out_Wn[gid]);
    }

    // Pipeline: xv0 = x[i], xv1 = x[i+T]; prefetch next pair each iter.
    float xv0 = x[gid];
    float xv1 = x[gid + T_STR];

    // Exactly 8 iterations; element m*T+gid covered with m=2k (A) and 2k+1 (B).
#pragma unroll 1
    for (int k = 0; k < 8; ++k) {
        const int i = gid + k * 2 * T_STR;

        // Prefetch the next pair FIRST (oldest position in VMEM queue).
        float xn0 = 0.0f, xn1 = 0.0f;
        if (k < 7) {                  // uniform branch
            xn0 = x[i + 2 * T_STR];
            xn1 = x[i + 3 * T_STR];
        }

        // Two independent SAR chains (bitmask state), interleaved for ILP.
        // sign(x-bs+1e-30) == (x>=bs ? +1 : -1) exactly (see R9 note);
        // t_k*c[m] == bit ? c[m] : 0.0f bit-exactly.
        unsigned m0 = 0u, m1 = 0u;    // bit j set => q_j = +1
        int m = M_ROWS - 1;
#pragma unroll
        for (int jj = 0; jj < B_BITS; ++jj) {
            const int j = B_BITS - 1 - jj;
            float bs0 = c[m], bs1 = c[m]; --m;   // Wn[m]*VREF
#pragma unroll
            for (int kk = j + 1; kk < B_BITS; ++kk) {
                bs0 += ((m0 >> kk) & 1u) ? c[m] : 0.0f;
                bs1 += ((m1 >> kk) & 1u) ? c[m] : 0.0f;
                --m;
            }
            if (xv0 >= bs0) m0 |= (1u << j);
            if (xv1 >= bs1) m1 |= (1u << j);
        }

        // q = sum_j bit_j * (0.225 * 2^j), ascending j (bit-exact vs ref).
        float acc0 = 0.0f, acc1 = 0.0f;
#pragma unroll
        for (int j = 0; j < B_BITS; ++j) {
            const float bwj = 0.225f * (float)(1 << j);
            acc0 += ((m0 >> j) & 1u) ? bwj : 0.0f;
            acc1 += ((m1 >> j) & 1u) ? bwj : 0.0f;
        }
        __builtin_nontemporal_store(acc0, &out_q[i]);
        __builtin_nontemporal_store(acc1, &out_q[i + T_STR]);

        // --- Q output: direct per-lane nt stores (q_j = bit ? +1 : -1).
        // Two f32x4 per element cover complementary halves of the same
        // 64B lines back-to-back -> write-combine candidates.
        f32x4 a0, a1, b0, b1;
#pragma unroll
        for (int j = 0; j < 4; ++j) {
            a0[j] = ((m0 >> j) & 1u)       ? 1.0f : -1.0f;
            a1[j] = ((m0 >> (j + 4)) & 1u) ? 1.0f : -1.0f;
            b0[j] = ((m1 >> j) & 1u)       ? 1.0f : -1.0f;
            b1[j] = ((m1 >> (j + 4)) & 1u) ? 1.0f : -1.0f;
        }
        f32x4* QA = (f32x4*)out_Q + (long long)i * 2;            // elem A
        f32x4* QB = (f32x4*)out_Q + ((long long)i + T_STR) * 2;  // elem B
        __builtin_nontemporal_store(a0, &QA[0]);
        __builtin_nontemporal_store(a1, &QA[1]);
        __builtin_nontemporal_store(b0, &QB[0]);
        __builtin_nontemporal_store(b1, &QB[1]);

        xv0 = xn0;
        xv1 = xn1;
    }
}

extern "C" void kernel_launch(void* const* d_in, const int* in_sizes, int n_in,
                              void* d_out, int out_size, void* d_ws, size_t ws_size,
                              hipStream_t stream) {
    const float* x  = (const float*)d_in[0];
    const float* W  = (const float*)d_in[1];
    const float* nz = (const float*)d_in[2];
    float* out = (float*)d_out;

    float* out_q  = out;
    float* out_Q  = out + (long long)N_TOT;
    float* out_Wn = out + (long long)N_TOT * 9;

    // 3072 blocks x 256 threads; stride T = 786432 (multiple of 24);
    // 8 unroll-2 iterations per thread; 8 blocks/CU = 32 waves/CU.
    sar_kernel<<<NBLK, BLK, 0, stream>>>(x, W, nz, out_q, out_Q, out_Wn);
}

// Round 14
// 94.650 us; speedup vs baseline: 2.2271x; 2.2271x over previous
//
#include <hip/hip_runtime.h>

// SAR quantizer: q, Q, Wn outputs.
// L=524288 rows, A=24 ADCs, B=8 bits, M=36 coefficient rows.
// VR = VREF = 1.8 / 2^3 = 0.225, noise scale = 0.01**0.5 = 0.1.
//
// R14 = R12 store path (LDS-staged dense nt stores — R13 proved per-lane
// nt partial-line stores DON'T write-combine: 211us) + ZERO-TAIL launch:
//   R12's 3072 blocks had only 2048 resident -> last 1024 ran at 16
//   waves/CU (two-phase tail, ~25-33% of runtime at half rate).
//   Now: BLK=192 (3 waves), NBLK=2560 = exactly 10 blocks/CU on 256 CUs,
//   ALL resident (30 waves/CU), zero launch tail. T = 491520 (mult of 24,
//   column trick intact). N/T = 25.6: threads do 13 pairs or 12 pairs +
//   1 single (wave-uniform bounds).

#define L_TOT   524288
#define A_ADC   24
#define M_ROWS  36
#define B_BITS  8
#define BLK     192
#define NBLK    2560
#define NXCD    8
#define N_TOT   (L_TOT * A_ADC)          // 12,582,912
#define T_STR   (NBLK * BLK)             // 491,520 (multiple of 24)

typedef float f32x4 __attribute__((ext_vector_type(4)));

// XOR bank-quad swizzle (involution, bijective on [0,128)).
__device__ __forceinline__ int swz(int c) { return c ^ ((c >> 3) & 7); }

__global__ __launch_bounds__(BLK) void sar_kernel(
    const float* __restrict__ x,
    const float* __restrict__ W,
    const float* __restrict__ nz,
    float* __restrict__ out_q,
    float* __restrict__ out_Q,
    float* __restrict__ out_Wn)
{
    // Bijective XCD swizzle (NBLK % 8 == 0).
    const int bid = blockIdx.x;
    const int sb  = (bid & (NXCD - 1)) * (NBLK / NXCD) + (bid >> 3);

    const int gid = sb * BLK + threadIdx.x;   // 0..T_STR-1, bijective
    const int a = gid % 24;          // ADC column (invariant: T_STR % 24 == 0)
    const int w = threadIdx.x >> 6;  // wave id in block (0..2)
    const int l = threadIdx.x & 63;  // lane

    __shared__ f32x4 stage[BLK / 64][2][128]; // 2 x 2KB per wave (12KB/blk)

    // Per-a coefficients: c[r] = (W[r][a] + noise[r][a]*0.1f) * 0.225f
    float c[M_ROWS];
#pragma unroll
    for (int r = 0; r < M_ROWS; ++r) {
        float wn = W[r * A_ADC + a] + nz[r * A_ADC + a] * 0.1f;
        c[r] = wn * 0.225f;
    }

    // Wn tail output (864 floats), once (gid is a bijection of thread id).
    if (gid < M_ROWS * A_ADC) {
        __builtin_nontemporal_store(W[gid] + nz[gid] * 0.1f, &out_Wn[gid]);
    }

    // SAR chain on one element value xv -> bitmask (bit j set => q_j = +1).
    // sign(x-bs+1e-30) == (x>=bs ? +1 : -1) exactly; bit?c:0.0f adds are
    // bit-exact vs reference's t*c (t in {0,1}; +-0.0 adds are no-ops).
    auto sar = [&](float xv) -> unsigned {
        unsigned msk = 0u;
        int m = M_ROWS - 1;
#pragma unroll
        for (int jj = 0; jj < B_BITS; ++jj) {
            const int j = B_BITS - 1 - jj;
            float bs = c[m]; --m;
#pragma unroll
            for (int kk = j + 1; kk < B_BITS; ++kk) {
                bs += ((msk >> kk) & 1u) ? c[m] : 0.0f;
                --m;
            }
            if (xv >= bs) msk |= (1u << j);
        }
        return msk;
    };
    // q scalar from mask: ascending-j sum, same fp order as reference.
    auto qsum = [](unsigned msk) -> float {
        float acc = 0.0f;
#pragma unroll
        for (int j = 0; j < B_BITS; ++j) {
            const float bwj = 0.225f * (float)(1 << j);
            acc += ((msk >> j) & 1u) ? bwj : 0.0f;
        }
        return acc;
    };
    // Q write for one element index via LDS buffer b (dense 1KB stores).
    auto qwrite = [&](int i, unsigned msk, int b) {
        f32x4 v0, v1;
#pragma unroll
        for (int j = 0; j < 4; ++j) {
            v0[j] = ((msk >> j) & 1u)       ? 1.0f : -1.0f;
            v1[j] = ((msk >> (j + 4)) & 1u) ? 1.0f : -1.0f;
        }
        const int c0 = 2 * l, c1 = 2 * l + 1;
        stage[w][b][swz(c0)] = v0;
        stage[w][b][swz(c1)] = v1;
        f32x4* Qp = (f32x4*)out_Q + (long long)(i - l) * 2;
        const int r0 = l, r1 = 64 + l;
        __builtin_nontemporal_store(stage[w][b][swz(r0)], &Qp[r0]);
        __builtin_nontemporal_store(stage[w][b][swz(r1)], &Qp[r1]);
    };

    // Pipeline: xv0 = x[i], xv1 = x[i+T] entering each pair-iteration.
    float xv0 = x[gid];                 // gid < T_STR < N ✓
    float xv1 = x[gid + T_STR];         // gid + T < 2T < N ✓

    int i = gid;
    // Pair loop: threads with gid < N-25T do 13 pairs; others 12 pairs
    // + 1 single. All guards are wave-uniform (gid contiguous in wave).
    while (i + T_STR < N_TOT) {
        // Prefetch next pair FIRST (oldest position in VMEM queue).
        float xn0 = 0.0f, xn1 = 0.0f;
        if (i + 2 * T_STR < N_TOT) xn0 = x[i + 2 * T_STR];
        if (i + 3 * T_STR < N_TOT) xn1 = x[i + 3 * T_STR];

        const unsigned m0 = sar(xv0);
        const unsigned m1 = sar(xv1);

        __builtin_nontemporal_store(qsum(m0), &out_q[i]);
        __builtin_nontemporal_store(qsum(m1), &out_q[i + T_STR]);
        qwrite(i, m0, 0);
        qwrite(i + T_STR, m1, 1);

        xv0 = xn0;
        xv1 = xn1;
        i += 2 * T_STR;
    }
    // Single-element tail (wave-uniform).
    if (i < N_TOT) {
        const unsigned m0 = sar(xv0);
        __builtin_nontemporal_store(qsum(m0), &out_q[i]);
        qwrite(i, m0, 0);
    }
}

extern "C" void kernel_launch(void* const* d_in, const int* in_sizes, int n_in,
                              void* d_out, int out_size, void* d_ws, size_t ws_size,
                              hipStream_t stream) {
    const float* x  = (const float*)d_in[0];
    const float* W  = (const float*)d_in[1];
    const float* nz = (const float*)d_in[2];
    float* out = (float*)d_out;

    float* out_q  = out;
    float* out_Q  = out + (long long)N_TOT;
    float* out_Wn = out + (long long)N_TOT * 9;

    // 2560 blocks x 192 threads = exactly 10 blocks/CU on 256 CUs, all
    // resident (30 waves/CU), zero launch tail.
    sar_kernel<<<NBLK, BLK, 0, stream>>>(x, W, nz, out_q, out_Q, out_Wn);
}